// Round 5
// baseline (214.039 us; speedup 1.0000x reference)
//
#include <hip/hip_runtime.h>
#include <hip/hip_bf16.h>

// Dilate = 5x5 per-channel max filter, SAME padding, (64,384,384,3) f32.
// Vertical-streaming, LDS-free, barrier-free, shuffle-based horizontal halo:
//   5 column strips of 60 output f4-cols (overlap 4): lane l of a wave owns
//   f4-col strip*60 - 2 + l.  Per row: ONE coalesced float4 load (clamped
//   addr, OOB cols -> -inf), neighbors A,B,D,E = own-column values of lanes
//   l-2..l+2 via __shfl (ds_bpermute, DS pipe - frees the VMEM pipe),
//   horizontal 5-max in regs, 5-deep vertical register ring, one exec-masked
//   float4 store (lanes 2..61, col < 288).  2-row-deep load prefetch.

#define Bn 64
#define H 384
#define ROWF 1152            // floats per image row (384*3)
#define ROWBYTES (ROWF * 4)
#define WF4 288              // float4s per row
#define RB 16                // output rows per wave
#define GROUPS 6             // 24 bands / 4 waves per block
#define STRIPS 5             // 5 * 60 = 300 >= 288 output f4 cols
#define SOUT 60              // output f4 cols per strip
#define NEGINF (-3.402823466e+38f)

__device__ __forceinline__ float4 max4(float4 a, float4 b) {
  return make_float4(fmaxf(a.x, b.x), fmaxf(a.y, b.y),
                     fmaxf(a.z, b.z), fmaxf(a.w, b.w));
}
__device__ __forceinline__ float4 shflup4(float4 v, int d) {
  return make_float4(__shfl_up(v.x, d), __shfl_up(v.y, d),
                     __shfl_up(v.z, d), __shfl_up(v.w, d));
}
__device__ __forceinline__ float4 shfldn4(float4 v, int d) {
  return make_float4(__shfl_down(v.x, d), __shfl_down(v.y, d),
                     __shfl_down(v.z, d), __shfl_down(v.w, d));
}

__global__ __launch_bounds__(256) void dilate5_kernel(
    const float* __restrict__ in, float* __restrict__ out) {
  const int wv = threadIdx.x >> 6;
  const int lane = threadIdx.x & 63;
  int t = blockIdx.x;
  const int strip = t % STRIPS; t /= STRIPS;
  const int grp = t % GROUPS;   t /= GROUPS;
  const int b = t;

  const int row0 = (grp * 4 + wv) * RB;
  const int col = strip * SOUT - 2 + lane;          // owned f4 col (may be OOB)
  const bool cvalid = (col >= 0) && (col < WF4);
  const int ccl = col < 0 ? 0 : (col > WF4 - 1 ? WF4 - 1 : col);
  const size_t coff = (size_t)ccl * 16;
  const bool willstore = (lane >= 2) && (lane < 62) && (col < WF4);

  const float4 ninf = make_float4(NEGINF, NEGINF, NEGINF, NEGINF);
  const char* __restrict__ imgb = (const char*)in + (size_t)b * H * ROWBYTES;
  char* __restrict__ outb = (char*)out + (size_t)b * H * ROWBYTES;

  // one coalesced load of this lane's own f4 column; OOB col -> -inf value
  auto loadC = [&](int gh) -> float4 {
    int ghc = gh < 0 ? 0 : (gh > H - 1 ? H - 1 : gh);
    float4 v = *reinterpret_cast<const float4*>(imgb + (size_t)ghc * ROWBYTES + coff);
    return cvalid ? v : ninf;
  };

  // horizontal 5-max from own C via cross-lane shuffles; uniform row mask
  auto hcomb = [&](int gh, float4 Cv) -> float4 {
    float4 A = shflup4(Cv, 2);
    float4 Bv = shflup4(Cv, 1);
    float4 D = shfldn4(Cv, 1);
    float4 E = shfldn4(Cv, 2);
    float4 h;
    h.x = fmaxf(fmaxf(fmaxf(A.z, Bv.y), fmaxf(Cv.x, Cv.w)), D.z);
    h.y = fmaxf(fmaxf(fmaxf(A.w, Bv.z), fmaxf(Cv.y, D.x)), D.w);
    h.z = fmaxf(fmaxf(fmaxf(Bv.x, Bv.w), fmaxf(Cv.z, D.y)), E.x);
    h.w = fmaxf(fmaxf(fmaxf(Bv.y, Cv.x), fmaxf(Cv.w, D.z)), E.y);
    if (gh < 0 || gh >= H) h = ninf;
    return h;
  };

  // ring init: hmax of rows row0-2 .. row0+1  (loads issued back to back)
  float4 C0 = loadC(row0 - 2);
  float4 C1 = loadC(row0 - 1);
  float4 C2 = loadC(row0);
  float4 C3 = loadC(row0 + 1);
  float4 Cc = loadC(row0 + 2);   // consumed in iter 0
  float4 Cn = loadC(row0 + 3);   // consumed in iter 1
  float4 r0 = hcomb(row0 - 2, C0);
  float4 r1 = hcomb(row0 - 1, C1);
  float4 r2 = hcomb(row0,     C2);
  float4 r3 = hcomb(row0 + 1, C3);

#pragma unroll 4
  for (int i = 0; i < RB; ++i) {
    const int o = row0 + i;
    float4 Cf = loadC(o + 4);          // prefetch 2 rows ahead (clamped)
    float4 r4 = hcomb(o + 2, Cc);
    float4 v = max4(max4(max4(r0, r1), max4(r2, r3)), r4);
    if (willstore)
      *reinterpret_cast<float4*>(outb + (size_t)o * ROWBYTES + coff) = v;
    r0 = r1; r1 = r2; r2 = r3; r3 = r4;
    Cc = Cn; Cn = Cf;
  }
}

extern "C" void kernel_launch(void* const* d_in, const int* in_sizes, int n_in,
                              void* d_out, int out_size, void* d_ws, size_t ws_size,
                              hipStream_t stream) {
  const float* images = (const float*)d_in[0];
  float* out = (float*)d_out;
  const int nblocks = Bn * GROUPS * STRIPS;  // 64*6*5 = 1920
  dilate5_kernel<<<nblocks, 256, 0, stream>>>(images, out);
}

// Round 6
// 198.511 us; speedup vs baseline: 1.0782x; 1.0782x over previous
//
#include <hip/hip_runtime.h>
#include <hip/hip_bf16.h>

// Dilate = 5x5 per-channel max filter, SAME padding, (64,384,384,3) f32.
// Deep-MLP batch streaming: each wave issues ALL 16 row-loads up-front
// (16 KB in flight), then consumes them in order (fine-grained vmcnt).
//   grid = 64 batch x 8 band-groups x 5 column-strips; 256-thr blocks.
//   Wave w handles band grp*4+w: RB=12 output rows (16 input rows incl halo).
//   Lane owns f4-col strip*60 - 2 + lane (strips overlap 4 for h-halo).
//   Per row: 1 coalesced float4 load (addr clamped, OOB col -> -inf value),
//   horizontal 5-max via cross-lane __shfl, 5-deep vertical ring, masked
//   float4 store per row during the drain phase.

#define Bn 64
#define H 384
#define ROWF 1152            // floats per image row (384*3)
#define ROWBYTES (ROWF * 4)
#define WF4 288              // float4s per row
#define RB 12                // output rows per wave
#define NLOAD (RB + 4)       // 16 input rows per wave
#define GROUPS 8             // (384/12)=32 bands / 4 waves per block
#define STRIPS 5             // 5 * 60 = 300 >= 288 output f4 cols
#define SOUT 60
#define NEGINF (-3.402823466e+38f)

__device__ __forceinline__ float4 max4(float4 a, float4 b) {
  return make_float4(fmaxf(a.x, b.x), fmaxf(a.y, b.y),
                     fmaxf(a.z, b.z), fmaxf(a.w, b.w));
}
__device__ __forceinline__ float4 shflup4(float4 v, int d) {
  return make_float4(__shfl_up(v.x, d), __shfl_up(v.y, d),
                     __shfl_up(v.z, d), __shfl_up(v.w, d));
}
__device__ __forceinline__ float4 shfldn4(float4 v, int d) {
  return make_float4(__shfl_down(v.x, d), __shfl_down(v.y, d),
                     __shfl_down(v.z, d), __shfl_down(v.w, d));
}

__global__ __launch_bounds__(256) void dilate5_kernel(
    const float* __restrict__ in, float* __restrict__ out) {
  const int wv = threadIdx.x >> 6;
  const int lane = threadIdx.x & 63;
  int t = blockIdx.x;
  const int strip = t % STRIPS; t /= STRIPS;
  const int grp = t % GROUPS;   t /= GROUPS;
  const int b = t;

  const int row0 = (grp * 4 + wv) * RB;
  const int col = strip * SOUT - 2 + lane;          // owned f4 col (may be OOB)
  const bool cvalid = (col >= 0) && (col < WF4);
  const int ccl = col < 0 ? 0 : (col > WF4 - 1 ? WF4 - 1 : col);
  const size_t coff = (size_t)ccl * 16;
  const bool willstore = (lane >= 2) && (lane < 62) && (col < WF4);

  const float4 ninf = make_float4(NEGINF, NEGINF, NEGINF, NEGINF);
  const char* __restrict__ imgb = (const char*)in + (size_t)b * H * ROWBYTES;
  char* __restrict__ outb = (char*)out + (size_t)b * H * ROWBYTES;

  // ---- Phase 1: issue ALL row loads back-to-back (16 KB in flight/wave) ----
  float4 raw[NLOAD];
#pragma unroll
  for (int j = 0; j < NLOAD; ++j) {
    int gh = row0 - 2 + j;
    int ghc = gh < 0 ? 0 : (gh > H - 1 ? H - 1 : gh);   // clamp address
    raw[j] = *reinterpret_cast<const float4*>(imgb + (size_t)ghc * ROWBYTES + coff);
  }

  // horizontal 5-max from own-column values via cross-lane shuffles
  auto hcomb = [&](int gh, float4 Cv) -> float4 {
    if (!cvalid) Cv = ninf;
    float4 A = shflup4(Cv, 2);
    float4 Bv = shflup4(Cv, 1);
    float4 D = shfldn4(Cv, 1);
    float4 E = shfldn4(Cv, 2);
    float4 h;
    h.x = fmaxf(fmaxf(fmaxf(A.z, Bv.y), fmaxf(Cv.x, Cv.w)), D.z);
    h.y = fmaxf(fmaxf(fmaxf(A.w, Bv.z), fmaxf(Cv.y, D.x)), D.w);
    h.z = fmaxf(fmaxf(fmaxf(Bv.x, Bv.w), fmaxf(Cv.z, D.y)), E.x);
    h.w = fmaxf(fmaxf(fmaxf(Bv.y, Cv.x), fmaxf(Cv.w, D.z)), E.y);
    if (gh < 0 || gh >= H) h = ninf;   // uniform row-validity select
    return h;
  };

  // ---- Phase 2: consume in order; ring of 5 hmax rows; store per row ----
  float4 r0 = hcomb(row0 - 2, raw[0]);
  float4 r1 = hcomb(row0 - 1, raw[1]);
  float4 r2 = hcomb(row0,     raw[2]);
  float4 r3 = hcomb(row0 + 1, raw[3]);

#pragma unroll
  for (int i = 0; i < RB; ++i) {
    const int o = row0 + i;
    float4 r4 = hcomb(o + 2, raw[i + 4]);
    float4 v = max4(max4(max4(r0, r1), max4(r2, r3)), r4);
    if (willstore)
      *reinterpret_cast<float4*>(outb + (size_t)o * ROWBYTES + coff) = v;
    r0 = r1; r1 = r2; r2 = r3; r3 = r4;
  }
}

extern "C" void kernel_launch(void* const* d_in, const int* in_sizes, int n_in,
                              void* d_out, int out_size, void* d_ws, size_t ws_size,
                              hipStream_t stream) {
  const float* images = (const float*)d_in[0];
  float* out = (float*)d_out;
  const int nblocks = Bn * GROUPS * STRIPS;  // 64*8*5 = 2560
  dilate5_kernel<<<nblocks, 256, 0, stream>>>(images, out);
}